// Round 12
// baseline (342.668 us; speedup 1.0000x reference)
//
#include <hip/hip_runtime.h>
#include <hip/hip_bf16.h>
#include <math.h>

// ---------------- static problem config ----------------
#define BB 4
#define LL 4096
#define DD 1024
#define KK 32
#define HH 32
#define AA 4
#define CKK 4
#define DI 1024
#define ZC 2080            // 2*DI + KK
#define FLATC 1024         // K*H
#define BL (BB * LL)       // 16384
#define ZLD 2080           // z row stride (bf16)
#define NPAD 2176          // W_in^T padded rows (17*128)

// scan config: chunk == conv block == 16 rows (was 32; halved to double
// conv_feat_scan's grid 512->1024 blocks = 2->4 blocks/CU TLP)
#define CCH 16
#define NCHK (LL / CCH)    // 256 chunks per b

// norm_head LDS strides (skewed to break lq-stride-128 bank conflicts)
#define GLD 1136           // zw row stride in u16 : col = o + (o>>7)*16
#define SGLD 1080          // sgf (silu-gate bf16) row stride: col = o + (o>>7)*8

typedef unsigned short u16;
typedef __attribute__((ext_vector_type(8))) short s16x8;
typedef __attribute__((ext_vector_type(4))) float f32x4;

__device__ __forceinline__ u16 f2bf(float f) {
  union { float f; unsigned int u; } v; v.f = f;
  unsigned int r = (v.u + 0x7FFFu + ((v.u >> 16) & 1u)) >> 16;
  return (u16)r;
}
__device__ __forceinline__ float bf2f(u16 u) {
  union { unsigned int i; float f; } x; x.i = ((unsigned int)u) << 16; return x.f;
}
__device__ __forceinline__ void gl_lds16(const void* g, void* l) {
  __builtin_amdgcn_global_load_lds(
      (const __attribute__((address_space(1))) unsigned int*)g,
      (__attribute__((address_space(3))) unsigned int*)l, 16, 0, 0);
}

// ---------------- fused prep: cast x + W_in^T + W_out^T + wprime ----------
__global__ __launch_bounds__(256) void prep_kernel(
    const float* __restrict__ x, u16* __restrict__ xbf,
    const float* __restrict__ W_in, u16* __restrict__ wbt,
    const float* __restrict__ W_out, u16* __restrict__ wobt,
    const float* __restrict__ W_re, const float* __restrict__ W_im,
    const float* __restrict__ ns, u16* __restrict__ wp) {
  __shared__ float t[32][33];
  const int bid = blockIdx.x;
  const int tid = threadIdx.x;
  if (bid < 8192) {                       // cast x
    const int i = (bid * 256 + tid) * 8;
    float4 a = *(const float4*)(x + i);
    float4 b = *(const float4*)(x + i + 4);
    s16x8 v;
    v[0] = (short)f2bf(a.x); v[1] = (short)f2bf(a.y);
    v[2] = (short)f2bf(a.z); v[3] = (short)f2bf(a.w);
    v[4] = (short)f2bf(b.x); v[5] = (short)f2bf(b.y);
    v[6] = (short)f2bf(b.z); v[7] = (short)f2bf(b.w);
    *(s16x8*)(xbf + i) = v;
    return;
  }
  if (bid >= 8192 + 2176 + 1024) {        // wprime
    const int i = (bid - (8192 + 2176 + 1024)) * 256 + tid;
    if (i < 1024) wp[i] = f2bf(ns[i >> 5] * W_re[i]);
    else {
      const int j = i - 1024;
      wp[i] = f2bf(ns[32 + (j >> 5)] * W_im[j]);
    }
    return;
  }
  // transpose tiles
  const float* src; u16* dst; int R, C, Cpad, r0, c0;
  if (bid < 8192 + 2176) {
    const int id = bid - 8192;
    src = W_in; dst = wbt; R = DD; C = ZC; Cpad = NPAD;
    r0 = (id & 31) * 32; c0 = (id >> 5) * 32;
  } else {
    const int id = bid - (8192 + 2176);
    src = W_out; dst = wobt; R = DI; C = DD; Cpad = DD;
    r0 = (id & 31) * 32; c0 = (id >> 5) * 32;
  }
  const int lr = tid >> 5, lc = tid & 31;
#pragma unroll
  for (int i = 0; i < 4; ++i) {
    const int r = r0 + i * 8 + lr, c = c0 + lc;
    float v = 0.f;
    if (r < R && c < C) v = src[(size_t)r * C + c];
    t[lc][i * 8 + lr] = v;
  }
  __syncthreads();
#pragma unroll
  for (int i = 0; i < 4; ++i) {
    const int dr = c0 + i * 8 + lr;
    const int dc = r0 + lc;
    if (dr < Cpad && dc < R) dst[(size_t)dr * R + dc] = f2bf(t[i * 8 + lr][lc]);
  }
}

// ---------------- 256x256 8-phase bf16 MFMA GEMM (T1+T2+T3+T4+T5) --------
// C[M,N] = A[M,K] * Bt[N,K]^T.  512 threads = 8 waves (2M x 4N), per-wave
// output 128x64 (8x4 fragments of 16x16), BK=64, NT = K/64 tiles (even).
// Both call sites have EXACT full tiles (no column guards needed).
//
// LDS 128KB: 8 half-regions of 16KB (128 rows x 64 cols bf16, row-major).
// 3-bit XOR swizzle: elem_col ^= (row&7)<<3; conflict-free in the K-loop.
// global_load_lds writes LINEAR dest, swizzle applied by pre-swizzling the
// GLOBAL source column (rule #21). Counted vmcnt(6) at phases 3/7 only;
// raw s_barrier (no vmcnt(0) drain). Staged epilogue (round 11): C-tile
// bounced through the dead LDS buffer, emitted as coalesced wide stores.
#define FENCE() asm volatile("" ::: "memory")
#define SBAR() do { FENCE(); __builtin_amdgcn_s_barrier(); FENCE(); } while (0)
#define VMCNT6() asm volatile("s_waitcnt vmcnt(6)" ::: "memory")

#define RA(s, h) (((s) * 2 + (h)) * 8192)
#define RB(s, h) (32768 + ((s) * 2 + (h)) * 8192)

template <int OUT_BF16>
__global__ __launch_bounds__(512, 2) void gemm256_8ph(
    const u16* __restrict__ A, const u16* __restrict__ Bt, void* __restrict__ C,
    int lda, int ldb, int ldc, int Kd, int Ncols) {
  __shared__ u16 lds[65536];   // 128 KiB
  const int tid = threadIdx.x;
  const int lane = tid & 63, wv = tid >> 6;
  const int wm = wv >> 2, wn = wv & 3;       // 2M x 4N wave grid
  const int lm = lane & 15, lq = lane >> 4;
  const int bm = blockIdx.x * 256, bn = blockIdx.y * 256;
  const int NT = Kd >> 6;                    // K tiles (even)
  const int NT2 = NT >> 1;

  const int rofs = wv * 8 + (lane >> 3);                 // region row
  const int cel = ((lane & 7) ^ (lane >> 3)) * 8;        // col elems, swz

  auto stageH = [&](const u16* __restrict__ G, int rowBase, int ld, int kt,
                    int regU16) {
    const u16* g0 = G + (size_t)(rowBase + rofs) * ld + (kt << 6) + cel;
    gl_lds16(g0, &lds[regU16 + wv * 512]);
    const u16* g1 = G + (size_t)(rowBase + 64 + rofs) * ld + (kt << 6) + cel;
    gl_lds16(g1, &lds[regU16 + 4096 + wv * 512]);
  };

  s16x8 Af[4][2], Bf[4][2];
  f32x4 acc[8][4];
  const f32x4 z4 = {0.f, 0.f, 0.f, 0.f};
#pragma unroll
  for (int i = 0; i < 8; ++i)
#pragma unroll
    for (int j = 0; j < 4; ++j) acc[i][j] = z4;

  const int xorw = (lm & 7) << 3;   // read-side swizzle XOR in u16 units

#define DSA(s, mh)                                                          \
  _Pragma("unroll") for (int f = 0; f < 4; ++f)                             \
  _Pragma("unroll") for (int ks = 0; ks < 2; ++ks)                          \
    Af[f][ks] = *(const s16x8*)&lds[RA(s, wm) +                             \
      (((((mh) * 4 + f) * 16 + lm) * 64 + ((ks * 32 + lq * 8) ^ xorw)))];

#define DSB(s)                                                              \
  _Pragma("unroll") for (int f = 0; f < 4; ++f)                             \
  _Pragma("unroll") for (int ks = 0; ks < 2; ++ks)                          \
    Bf[f][ks] = *(const s16x8*)&lds[RB(s, wn >> 1) +                        \
      ((((wn & 1) * 64 + f * 16 + lm) * 64 + ((ks * 32 + lq * 8) ^ xorw)))];

#define QUAD(mh, nh)                                                        \
  do {                                                                      \
    __builtin_amdgcn_s_setprio(1);                                          \
    _Pragma("unroll") for (int f = 0; f < 4; ++f)                           \
    _Pragma("unroll") for (int n = 0; n < 2; ++n)                           \
    _Pragma("unroll") for (int ks = 0; ks < 2; ++ks)                        \
      acc[(mh) * 4 + f][(nh) * 2 + n] =                                     \
          __builtin_amdgcn_mfma_f32_16x16x32_bf16(                          \
              Af[f][ks], Bf[(nh) * 2 + n][ks],                              \
              acc[(mh) * 4 + f][(nh) * 2 + n], 0, 0, 0);                    \
    __builtin_amdgcn_s_setprio(0);                                          \
  } while (0)

  // ---- prologue: 7 halves (t0 full + t1 B0,B1,A0); t1A1 comes at p0 ----
  stageH(A, bm, lda, 0, RA(0, 0));
  stageH(A, bm + 128, lda, 0, RA(0, 1));
  stageH(Bt, bn, ldb, 0, RB(0, 0));
  stageH(Bt, bn + 128, ldb, 0, RB(0, 1));
  stageH(Bt, bn, ldb, 1, RB(1, 0));
  stageH(Bt, bn + 128, ldb, 1, RB(1, 1));
  stageH(A, bm, lda, 1, RA(1, 0));
  VMCNT6();        // first 4 halves (tile 0) landed
  SBAR();

#pragma unroll 1
  for (int t = 0; t < NT2; ++t) {
    const int T2 = 2 * t + 2, T3 = 2 * t + 3;
    // -------- tile 2t from slot 0 --------
    DSA(0, 0); DSB(0);
    stageH(A, bm + 128, lda, 2 * t + 1, RA(1, 1));   // s1A1 of tile 2t+1
    SBAR();
    QUAD(0, 0);
    SBAR();
    if (T2 < NT) stageH(Bt, bn, ldb, T2, RB(0, 0));
    SBAR();
    QUAD(0, 1);
    SBAR();
    DSA(0, 1);
    if (T2 < NT) stageH(Bt, bn + 128, ldb, T2, RB(0, 1));
    SBAR();
    QUAD(1, 0);
    SBAR();
    if (T2 < NT) stageH(A, bm, lda, T2, RA(0, 0));
    SBAR();
    QUAD(1, 1);
    VMCNT6();      // slot1 (tile 2t+1) fully landed before p4 reads
    SBAR();
    // -------- tile 2t+1 from slot 1 --------
    DSA(1, 0); DSB(1);
    if (T2 < NT) stageH(A, bm + 128, lda, T2, RA(0, 1));
    SBAR();
    QUAD(0, 0);
    SBAR();
    if (T3 < NT) stageH(Bt, bn, ldb, T3, RB(1, 0));
    SBAR();
    QUAD(0, 1);
    SBAR();
    DSA(1, 1);
    if (T3 < NT) stageH(Bt, bn + 128, ldb, T3, RB(1, 1));
    SBAR();
    QUAD(1, 0);
    SBAR();
    if (T3 < NT) stageH(A, bm, lda, T3, RA(1, 0));
    SBAR();
    QUAD(1, 1);
    VMCNT6();      // slot0 (tile 2t+2) fully landed before next p0 reads
    SBAR();
  }

  // ---- staged epilogue: LDS tile -> coalesced wide stores ----
  asm volatile("s_waitcnt vmcnt(0)" ::: "memory");   // drain stray loads
  SBAR();                                            // lds now reusable
  if (OUT_BF16) {
    // full 256x256 bf16 tile = exactly 128 KB
#pragma unroll
    for (int f = 0; f < 8; ++f)
#pragma unroll
      for (int n = 0; n < 4; ++n)
#pragma unroll
        for (int r = 0; r < 4; ++r) {
          const int row = wm * 128 + f * 16 + lq * 4 + r;
          const int col = wn * 64 + n * 16 + lm;
          lds[row * 256 + col] = f2bf(acc[f][n][r]);
        }
    SBAR();
    // per instruction: wave writes 2 rows x 512B fully contiguous
#pragma unroll
    for (int it2 = 0; it2 < 16; ++it2) {
      const int row = it2 * 16 + wv * 2 + (lane >> 5);
      const int cb2 = (lane & 31) * 8;
      s16x8 v = *(const s16x8*)&lds[row * 256 + cb2];
      *(s16x8*)((u16*)C + (size_t)(bm + row) * ldc + bn + cb2) = v;
    }
  } else {
    // f32 tile = 256 KB: two 128-row halves of exactly 128 KB
    float* ldsf = (float*)lds;
#pragma unroll
    for (int h = 0; h < 2; ++h) {
      if (wm == h) {
#pragma unroll
        for (int f = 0; f < 8; ++f)
#pragma unroll
          for (int n = 0; n < 4; ++n)
#pragma unroll
            for (int r = 0; r < 4; ++r) {
              const int row = f * 16 + lq * 4 + r;   // local in half
              const int col = wn * 64 + n * 16 + lm;
              ldsf[row * 256 + col] = acc[f][n][r];
            }
      }
      SBAR();
      // per instruction: wave writes one full row (1KB contiguous)
#pragma unroll
      for (int it2 = 0; it2 < 16; ++it2) {
        const int row = it2 * 8 + wv;                // 0..127
        f32x4 v = *(const f32x4*)&ldsf[row * 256 + lane * 4];
        *(f32x4*)((float*)C + (size_t)(bm + h * 128 + row) * ldc + bn + lane * 4) = v;
      }
      SBAR();
    }
  }
#undef DSA
#undef DSB
#undef QUAD
}

// ---------------- score GEMM: z[:,2048:2080] = x @ W_in[:,2048:2080] -----
__global__ __launch_bounds__(256) void score_gemm(
    const u16* __restrict__ A, const u16* __restrict__ Bt,
    u16* __restrict__ z) {
  __shared__ u16 As[8192];   // 16 units x 512 elems (128 rows x 64 k)
  __shared__ u16 Bs[2048];   // 4 units  (32 rows x 64 k)
  const int tid = threadIdx.x;
  const int lane = tid & 63, wv = tid >> 6;
  const int lm = lane & 15, lq = lane >> 4;
  const int bm = blockIdx.x * 128;

  const f32x4 z4 = {0.f, 0.f, 0.f, 0.f};
  f32x4 acc[2][2];
#pragma unroll
  for (int i = 0; i < 2; ++i)
#pragma unroll
    for (int j = 0; j < 2; ++j) acc[i][j] = z4;

  for (int k0 = 0; k0 < DD; k0 += 64) {
    __syncthreads();
#pragma unroll
    for (int t = 0; t < 5; ++t) {
      const int idx = wv * 5 + t;            // 0..19
      if (idx < 16) {                        // A unit (mt, kt)
        const int mt = idx >> 1, kt = idx & 1;
        const u16* g = A + (size_t)(bm + mt * 16 + lm) * DD + k0 + kt * 32 + lq * 8;
        gl_lds16(g, &As[idx * 512]);
      } else {                               // B unit (nt, kt)
        const int bidx = idx - 16;
        const int nt = bidx >> 1, kt = bidx & 1;
        const u16* g = Bt + (size_t)(2048 + nt * 16 + lm) * DD + k0 + kt * 32 + lq * 8;
        gl_lds16(g, &Bs[bidx * 512]);
      }
    }
    __syncthreads();
#pragma unroll
    for (int kt = 0; kt < 2; ++kt) {
      s16x8 af[2], bfb[2];
#pragma unroll
      for (int i = 0; i < 2; ++i) {
        const int mt = wv * 2 + i;
        af[i] = *(const s16x8*)&As[(mt * 2 + kt) * 512 + lane * 8];
        bfb[i] = *(const s16x8*)&Bs[(i * 2 + kt) * 512 + lane * 8];
      }
#pragma unroll
      for (int i = 0; i < 2; ++i)
#pragma unroll
        for (int j = 0; j < 2; ++j)
          acc[i][j] = __builtin_amdgcn_mfma_f32_16x16x32_bf16(af[i], bfb[j], acc[i][j], 0, 0, 0);
    }
  }
#pragma unroll
  for (int i = 0; i < 2; ++i)
#pragma unroll
    for (int j = 0; j < 2; ++j)
#pragma unroll
      for (int r = 0; r < 4; ++r) {
        const int row = bm + wv * 32 + i * 16 + lq * 4 + r;
        const int col = 2048 + j * 16 + lm;
        z[(size_t)row * ZLD + col] = f2bf(acc[i][j][r]);
      }
}

// ---------------- conv + p_w + features + chunk-local cumsum --------------
// One block = one 16-row chunk (CCH=16: 1024 blocks = 4 blocks/CU, double
// the TLP of the 32-row version for this latency-bound kernel). re/im
// chunk-local cumsums stored BF16 (mbf [BL][2048]); den cumsum f32 in dbuf.
__global__ __launch_bounds__(256) void conv_feat_scan(
    const u16* __restrict__ z, const float* __restrict__ kern,
    const float* __restrict__ theta, const float* __restrict__ decay,
    const float* __restrict__ anchor, const float* __restrict__ sscale,
    u16* __restrict__ mbf, float* __restrict__ dbuf,
    float* __restrict__ part) {
  __shared__ float pbuf[CCH][KK];        // raw p_w per (row, head)
  __shared__ u16 zt[(CCH + 3) * 256];    // staged z panel (9.5 KB)
  __shared__ u16 st[(CCH + 3) * 32];     // staged score panel (1.2 KB)
  const int tid = threadIdx.x;
  const int r0 = blockIdx.x * CCH;           // global row base
  const bool first = ((r0 & (LL - 1)) == 0);
  const int chunk = blockIdx.x;              // global chunk id

  // stage score panel rows r0-3 .. r0+CCH-1 ((CCH+3) x 32 u16, vectorized)
  if (tid < (CCH + 3) * 4) {
    const int row = tid >> 2, q8 = (tid & 3) * 8;
    s16x8 v = {0, 0, 0, 0, 0, 0, 0, 0};
    if (!(first && row < 3))
      v = *(const s16x8*)(z + (size_t)(r0 - 3 + row) * ZLD + 2048 + q8);
    *(s16x8*)&st[row * 32 + q8] = v;
  }
  __syncthreads();

  // phase A: p_w for CCH rows x 32 heads (2 items/thread), scores from LDS
#pragma unroll
  for (int q = 0; q < (CCH * KK) / 256; ++q) {
    const int item = q * 256 + tid;
    const int row = item >> 5, k = item & 31;
    float v = 0.f;
#pragma unroll
    for (int w = 0; w < CKK; ++w)
      v = fmaf(bf2f(st[(row + w) * 32 + k]), kern[w * ZC + 2048 + k], v);
    const int l = (r0 + row) & (LL - 1);
    const float slope = (k < KK - AA) ? decay[k] : anchor[k - (KK - AA)];
    const float sp = log1pf(__expf(slope));
    const float lw = (k < KK - AA) ? (-sp * (float)(LL - 1 - l)) : (-sp * (float)l);
    pbuf[row][k] = __expf(sscale[k] * v + lw);
  }
  __syncthreads();

  // phase B: den chunk-local cumsum -> dbuf f32 (32 threads)
  if (tid < KK) {
    float run = 0.f;
#pragma unroll
    for (int row = 0; row < CCH; ++row) {
      run += pbuf[row][tid];
      dbuf[(size_t)(r0 + row) * KK + tid] = run;
    }
    part[(size_t)chunk * ZC + tid] = run;
  }

  // phase C: features + chunk-local cumsum. Per it: stage (CCH+3)x256 panel
  // (vector loads), then rolling 4-tap conv from LDS.
#pragma unroll 1
  for (int it = 0; it < 4; ++it) {
    __syncthreads();   // protect zt reuse (and pbuf/phase-B on it==0)
    for (int u = tid; u < (CCH + 3) * 32; u += 256) {
      const int row = u >> 5, q8 = (u & 31) * 8;
      s16x8 v = {0, 0, 0, 0, 0, 0, 0, 0};
      if (!(first && row < 3))
        v = *(const s16x8*)(z + (size_t)(r0 - 3 + row) * ZLD + it * 256 + q8);
      *(s16x8*)&zt[row * 256 + q8] = v;
    }
    __syncthreads();

    const int c = it * 256 + tid;            // 0..1023
    const float kw0 = kern[0 * ZC + c], kw1 = kern[1 * ZC + c];
    const float kw2 = kern[2 * ZC + c], kw3 = kern[3 * ZC + c];
    const float th = theta[c];
    const int head = c >> 5;
    float h0 = bf2f(zt[0 * 256 + tid]);
    float h1 = bf2f(zt[1 * 256 + tid]);
    float h2 = bf2f(zt[2 * 256 + tid]);
    float sre = 0.f, sim = 0.f;
#pragma unroll 4
    for (int row = 0; row < CCH; ++row) {
      const float h3 = bf2f(zt[(row + 3) * 256 + tid]);
      float v = h0 * kw0;
      v = fmaf(h1, kw1, v);
      v = fmaf(h2, kw2, v);
      v = fmaf(h3, kw3, v);
      h0 = h1; h1 = h2; h2 = h3;
      const float phi = v * th;
      float sv, cv;
      __sincosf(phi, &sv, &cv);
      const float p = pbuf[row][head];
      sre = fmaf(p, cv, sre);
      sim = fmaf(p, sv, sim);
      u16* mrow = mbf + (size_t)(r0 + row) * 2048;
      mrow[c] = f2bf(sre);
      mrow[1024 + c] = f2bf(sim);
    }
    part[(size_t)chunk * ZC + KK + c] = sre;
    part[(size_t)chunk * ZC + KK + FLATC + c] = sim;
  }
}

// ---------------- exclusive scan of chunk totals (256 chunks per b) -------
__global__ __launch_bounds__(256) void scan_offsets_kernel(float* __restrict__ part) {
  const int c = blockIdx.x * 256 + threadIdx.x;
  const int b = blockIdx.z;
  if (c >= ZC) return;
  float run = 0.f;
#pragma unroll 8
  for (int i = 0; i < NCHK; ++i) {
    const size_t idx = ((size_t)b * NCHK + i) * ZC + c;
    const float t = part[idx];
    part[idx] = run;
    run += t;
  }
}

// ---------------- norm_head via MFMA ----------------
// Block = 8 bl rows (4 waves x 2 rows). mbf holds CHUNK-LOCAL cumsum bf16;
// global prefix = bf2f(local) + part[chunk] (f32), den from dbuf f32.
// Gate phase-split: silu(conv(z_gate)) precomputed with vector LDS z reads
// + direct global kern f32 reads. sgf stored BF16 in the zw overlay ->
// LDS allocation = max(zw 25KB, sgf 17.3KB) = 25KB -> 6 blocks/CU (was 4
// at 34.5KB): +50% TLP for this latency-bound kernel. Precision: sil bf16
// (<=0.4% rel) multiplies a value that is rounded to bf16 on store anyway.
__global__ __launch_bounds__(256) void norm_head_mfma(
    const u16* __restrict__ mbf, const float* __restrict__ dbuf,
    const u16* __restrict__ z, const float* __restrict__ kern,
    const u16* __restrict__ wp, const float* __restrict__ part,
    u16* __restrict__ g) {
  // manual LDS partition: phase 1 zw (11*GLD*2 = 24992B);
  // phase 2 overlays sgf bf16 (8*SGLD*2 = 17280B) on the same region.
  __shared__ __align__(16) char smem[24992];
  u16* zw = (u16*)smem;                       // 11*GLD u16
  u16* sgf = (u16*)smem;                      // 8*SGLD u16 (overlay)
  const int tid = threadIdx.x;
  const int r0 = blockIdx.x * 8;
  const bool first = ((r0 & (LL - 1)) == 0);
  const int lane = tid & 63, wv = tid >> 6;
  const int lm = lane & 15, lq = lane >> 4;
  // chunk offsets row for this block (8 rows always within one 16-row chunk)
  const float* po = part + (size_t)(blockIdx.x >> 1) * ZC;

  // stage z gate cols (1024..2047), rows r0-3 .. r0+7, with skew
  for (int idx = tid; idx < 11 * 128; idx += 256) {
    const int i = idx >> 7, c8 = idx & 127;
    s16x8 v = {0, 0, 0, 0, 0, 0, 0, 0};
    if (!(first && i < 3))
      v = *(const s16x8*)(z + (size_t)(r0 - 3 + i) * ZLD + 1024 + c8 * 8);
    *(s16x8*)&zw[i * GLD + c8 * 8 + (c8 >> 4) * 16] = v;
  }

  // B fragments (same for all rows): lane(lm,lq) holds W'[lq*8+j][nt*16+lm]
  s16x8 bre[2], bim[2];
#pragma unroll
  for (int nt = 0; nt < 2; ++nt)
#pragma unroll
    for (int jj = 0; jj < 8; ++jj) {
      bre[nt][jj] = (short)wp[(lq * 8 + jj) * 32 + nt * 16 + lm];
      bim[nt][jj] = (short)wp[1024 + (lq * 8 + jj) * 32 + nt * 16 + lm];
    }
  __syncthreads();

  // ---- gate phase: silu(conv) for rows rh*4..+3, cols cb..cb+7 ----
  const int rh = tid >> 7;            // 0..1
  const int cb = (tid & 127) * 8;     // col base 0..1016
  float gbuf[4][8];
  {
    const int szb = cb + (cb >> 7) * 16;   // zw skewed col base
#pragma unroll
    for (int j = 0; j < 4; ++j) {
      const int rr = rh * 4 + j;
      float gv[8] = {0.f, 0.f, 0.f, 0.f, 0.f, 0.f, 0.f, 0.f};
#pragma unroll
      for (int w_ = 0; w_ < 4; ++w_) {
        s16x8 zv = *(const s16x8*)&zw[(rr + w_) * GLD + szb];
        float4 ka = *(const float4*)(kern + w_ * ZC + 1024 + cb);
        float4 kb = *(const float4*)(kern + w_ * ZC + 1024 + cb + 4);
        gv[0] = fmaf(bf2f((u16)zv[0]), ka.x, gv[0]);
        gv[1] = fmaf(bf2f((u16)zv[1]), ka.y, gv[1]);
        gv[2] = fmaf(bf2f((u16)zv[2]), ka.z, gv[2]);
        gv[3] = fmaf(bf2f((u16)zv[3]), ka.w, gv[3]);
        gv[4] = fmaf(bf2f((u16)zv[4]), kb.x, gv[4]);
        gv[5] = fmaf(bf2f((u16)zv[5]), kb.y, gv[5]);
        gv[6] = fmaf(bf2f((u16)zv[6]), kb.z, gv[6]);
        gv[7] = fmaf(bf2f((u16)zv[7]), kb.w, gv[7]);
      }
#pragma unroll
      for (int e = 0; e < 8; ++e)
        gbuf[j][e] = gv[e] * (1.0f / (1.0f + __expf(-gv[e])));
    }
  }
  __syncthreads();   // all zw reads complete (sgf overlays zw)
  {
    const int sgc = cb + (cb >> 7) * 8;    // sgf skewed col base
#pragma unroll
    for (int j = 0; j < 4; ++j) {
      s16x8 v;
#pragma unroll
      for (int e = 0; e < 8; ++e) v[e] = (short)f2bf(gbuf[j][e]);
      *(s16x8*)&sgf[(rh * 4 + j) * SGLD + sgc] = v;
    }
  }
  __syncthreads();   // sgf visible

  const f32x4 z4 = {0.f, 0.f, 0.f, 0.f};
#pragma unroll 1
  for (int rr2 = 0; rr2 < 2; ++rr2) {
    const int rr = wv * 2 + rr2;          // 0..7 within block
    const int bl = r0 + rr;
    const float* dd = dbuf + (size_t)bl * KK;
    const float den0 = dd[lm] + po[lm];
    const float den1 = dd[16 + lm] + po[16 + lm];

#pragma unroll
    for (int khalf = 0; khalf < 2; ++khalf) {
      // A loads: re/im bf16 for (bl, k = khalf*16+lm), hp = lq*8..lq*8+7
      const int co = (khalf * 16 + lm) * 32 + lq * 8;
      const u16* rp = mbf + (size_t)bl * 2048 + co;
      s16x8 vre = *(const s16x8*)rp;
      s16x8 vim = *(const s16x8*)(rp + 1024);
      const float* pp = po + KK + co;
      float4 qa = *(const float4*)pp;
      float4 qb = *(const float4*)(pp + 4);
      float4 ja = *(const float4*)(pp + FLATC);
      float4 jb = *(const float4*)(pp + FLATC + 4);
      float re[8], im[8];
      re[0] = bf2f((u16)vre[0]) + qa.x; re[1] = bf2f((u16)vre[1]) + qa.y;
      re[2] = bf2f((u16)vre[2]) + qa.z; re[3] = bf2f((u16)vre[3]) + qa.w;
      re[4] = bf2f((u16)vre[4]) + qb.x; re[5] = bf2f((u16)vre[5]) + qb.y;
      re[6] = bf2f((u16)vre[6]) + qb.z; re[7] = bf2f((u16)vre[7]) + qb.w;
      im[0] = bf2f((u16)vim[0]) + ja.x; im[1] = bf2f((u16)vim[1]) + ja.y;
      im[2] = bf2f((u16)vim[2]) + ja.z; im[3] = bf2f((u16)vim[3]) + ja.w;
      im[4] = bf2f((u16)vim[4]) + jb.x; im[5] = bf2f((u16)vim[5]) + jb.y;
      im[6] = bf2f((u16)vim[6]) + jb.z; im[7] = bf2f((u16)vim[7]) + jb.w;

      float ssq = 0.f;
#pragma unroll
      for (int e = 0; e < 8; ++e) {
        ssq = fmaf(re[e], re[e], ssq);
        ssq = fmaf(im[e], im[e], ssq);
      }
      ssq += __shfl_xor(ssq, 16);
      ssq += __shfl_xor(ssq, 32);
      const float den = khalf ? den1 : den0;
      const float inv = 1.0f / fmaxf(den, 1e-4f);
      const float scale = inv * rsqrtf(ssq * inv * inv * (1.0f / 64.0f) + 1e-5f);

      s16x8 afr, afi;
#pragma unroll
      for (int e = 0; e < 8; ++e) {
        afr[e] = (short)f2bf(re[e] * scale);
        afi[e] = (short)f2bf(im[e] * scale);
      }

      f32x4 acc[2];
#pragma unroll
      for (int nt = 0; nt < 2; ++nt) {
        acc[nt] = __builtin_amdgcn_mfma_f32_16x16x32_bf16(afr, bre[nt], z4, 0, 0, 0);
        acc[nt] = __builtin_amdgcn_mfma_f32_16x16x32_bf16(afi, bim[nt], acc[nt], 0, 0, 0);
      }

      // epilogue: D row = lq*4+r (k offset), col = lm (h offset)
      u16* grow = g + (size_t)bl * 1024;
#pragma unroll
      for (int nt = 0; nt < 2; ++nt) {
#pragma unroll
        for (int r = 0; r < 4; ++r) {
          const int k = khalf * 16 + lq * 4 + r;
          const int o = k * 32 + nt * 16 + lm;
          const float sil = bf2f(sgf[rr * SGLD + o + (o >> 7) * 8]);
          grow[o] = f2bf(acc[nt][r] * sil);
        }
      }
    }
  }
}

// ---------------- launch ----------------
extern "C" void kernel_launch(void* const* d_in, const int* in_sizes, int n_in,
                              void* d_out, int out_size, void* d_ws, size_t ws_size,
                              hipStream_t stream) {
  const float* x      = (const float*)d_in[0];
  const float* W_in   = (const float*)d_in[1];
  const float* kern   = (const float*)d_in[2];
  const float* theta  = (const float*)d_in[3];
  const float* decay  = (const float*)d_in[4];
  const float* anchor = (const float*)d_in[5];
  const float* sscale = (const float*)d_in[6];
  const float* W_re   = (const float*)d_in[7];
  const float* W_im   = (const float*)d_in[8];
  const float* nscale = (const float*)d_in[9];
  const float* W_out  = (const float*)d_in[10];
  float* out = (float*)d_out;

  // workspace layout (177.4 MiB total; < proven 199 MiB budget):
  //   mbf  [BL][2048] u16  @ 0          (67.11 MB)  xbf aliases (dead pre-conv)
  //   zbf  [BL][ZLD]  u16  @ 67108864   (68.16 MB)
  //   dbuf [BL][32]   f32  @ 135266304  ( 2.10 MB)
  //   part [1024][ZC] f32  @ 137363456  ( 8.52 MB)
  //   wp   [2048]     u16  @ 145883136  ( 4 KB)
  //   wbt  [NPAD][DD] u16  @ 145887232  ( 4.46 MB)
  //   g    [BL][1024] u16  @ 150343680  (33.55 MB)
  //   wobt [DD][DD]   u16  @ 183898112  ( 2.10 MB)
  char* w = (char*)d_ws;
  u16* mbf   = (u16*)w;
  u16* xbf   = (u16*)w;                          // alias: dead once gemm1 done
  u16* zbf   = (u16*)(w + 67108864ull);
  float* dbuf = (float*)(w + 135266304ull);
  float* part = (float*)(w + 137363456ull);
  u16* wp    = (u16*)(w + 145883136ull);
  u16* wbt   = (u16*)(w + 145887232ull);
  u16* g     = (u16*)(w + 150343680ull);
  u16* wobt  = (u16*)(w + 183898112ull);

  // 1) fused prep: cast x + W_in^T + W_out^T + wprime (one dispatch)
  prep_kernel<<<dim3(8192 + 2176 + 1024 + 8), 256, 0, stream>>>(
      x, xbf, W_in, wbt, W_out, wobt, W_re, W_im, nscale, wp);

  // 2a) score cols 2048..2079 of z (tiny GEMM, keeps main grid clean)
  score_gemm<<<dim3(BL / 128), 256, 0, stream>>>(xbf, wbt, zbf);

  // 2b) GEMM1 main: z[:, :2048] = x @ W_in[:, :2048]. grid = 64x8 = 512
  // blocks = exactly 2 clean dispatch rounds at 1 block/CU.
  gemm256_8ph<1><<<dim3(BL / 256, 8), 512, 0, stream>>>(
      xbf, wbt, zbf, DD, DD, ZLD, DD, ZC);

  // 3) conv + p_w + features + chunk-local cumsum -> mbf(bf16), dbuf, part
  conv_feat_scan<<<dim3(BL / CCH), 256, 0, stream>>>(
      zbf, kern, theta, decay, anchor, sscale, mbf, dbuf, part);

  // 4) exclusive scan of chunk totals (in-place on part)
  {
    dim3 grid2((ZC + 255) / 256, 1, BB);
    scan_offsets_kernel<<<grid2, 256, 0, stream>>>(part);
  }

  // 5) normalize + RMS + head matmuls (MFMA) + gate -> g (compact bf16)
  norm_head_mfma<<<dim3(BL / 8), 256, 0, stream>>>(
      mbf, dbuf, zbf, kern, wp, part, g);

  // 6) GEMM2: out = g @ W_out (f32 out), lda = 1024 compact
  gemm256_8ph<0><<<dim3(BL / 256, DD / 256), 512, 0, stream>>>(
      g, wobt, out, 1024, DD, DD, DI, DD);
}